// Round 1
// baseline (72246.735 us; speedup 1.0000x reference)
//
#include <hip/hip_runtime.h>

#define CIN 64
#define COUT 128
#define NPIX 1024        // 32*32
#define YP_PLANE 1156    // 34*34
#define PITCH 36         // LDS pitch for 34-wide planes (16B-aligned rows)
#define UPITCH 40        // LDS pitch for 36-wide padded residual planes
#define NUM_ITERS 500
#define LR_F 0.001f

// ---- helpers ----------------------------------------------------------------

// Stage a 34x34 plane (contiguous 1156 floats, 16B-aligned) into pitch-36 LDS.
__device__ __forceinline__ void stage_plane34(const float* __restrict__ g, float* s, int tid) {
  for (int i4 = tid; i4 < 289; i4 += 256) {   // 289 float4 = 1156 floats
    float4 v = ((const float4*)g)[i4];
    int e = i4 * 4;
    int ry = e / 34, rx = e - ry * 34;
    float vv[4] = {v.x, v.y, v.z, v.w};
#pragma unroll
    for (int k = 0; k < 4; ++k) {
      s[ry * PITCH + rx] = vv[k];
      if (++rx == 34) { rx = 0; ++ry; }
    }
  }
}

// Stage a 32x32 plane into pitch-36 LDS at offset (+1,+1); border stays zero.
__device__ __forceinline__ void stage_x(const float* __restrict__ g, float* s, int tid) {
  int ry = tid >> 3, rx = (tid & 7) * 4;
  float4 v = *(const float4*)(g + ry * 32 + rx);
  float* d = s + (ry + 1) * PITCH + rx + 1;
  d[0] = v.x; d[1] = v.y; d[2] = v.z; d[3] = v.w;
}

// Stage a 32x32 residual plane into pitch-40 LDS at offset (+2,+2); border stays zero.
__device__ __forceinline__ void stage_r(const float* __restrict__ g, float* s, int tid) {
  int ry = tid >> 3, rx = (tid & 7) * 4;
  float4 v = *(const float4*)(g + ry * 32 + rx);
  float* d = s + (ry + 2) * UPITCH + rx + 2;
  d[0] = v.x; d[1] = v.y; d[2] = v.z; d[3] = v.w;
}

// acc[k] += sum_{di,dj} s[(y+di)*PITCH + x0+k+dj] * w9[di*3+dj], k=0..3
__device__ __forceinline__ void conv_acc(const float* s, const float* __restrict__ w9,
                                         int y, int x0, float acc[4]) {
  float w[9];
#pragma unroll
  for (int i = 0; i < 9; ++i) w[i] = w9[i];
#pragma unroll
  for (int di = 0; di < 3; ++di) {
    const float* row = s + (y + di) * PITCH + x0;
    float4 v4 = *(const float4*)row;
    float2 v2 = *(const float2*)(row + 4);
    float v[6] = {v4.x, v4.y, v4.z, v4.w, v2.x, v2.y};
#pragma unroll
    for (int dj = 0; dj < 3; ++dj) {
      float wv = w[di * 3 + dj];
#pragma unroll
      for (int k = 0; k < 4; ++k) acc[k] = fmaf(v[k + dj], wv, acc[k]);
    }
  }
}

// transposed-conv accumulate: acc[k] += sum_{di,dj} s[(p+2-di)*UPITCH + q0+k+2-dj] * w9[di*3+dj]
__device__ __forceinline__ void tconv_acc(const float* s, const float* __restrict__ w9,
                                          int p, int q0, float acc[4]) {
  float w[9];
#pragma unroll
  for (int i = 0; i < 9; ++i) w[i] = w9[i];
#pragma unroll
  for (int dr = 0; dr < 3; ++dr) {           // dr = 2-di
    const float* row = s + (p + dr) * UPITCH + q0;
    float4 v4 = *(const float4*)row;
    float2 v2 = *(const float2*)(row + 4);
    float v[6] = {v4.x, v4.y, v4.z, v4.w, v2.x, v2.y};
#pragma unroll
    for (int dc = 0; dc < 3; ++dc) {         // dc = 2-dj
      float wv = w[(2 - dr) * 3 + (2 - dc)];
#pragma unroll
      for (int k = 0; k < 4; ++k) acc[k] = fmaf(v[k + dc], wv, acc[k]);
    }
  }
}

// ---- kernels ----------------------------------------------------------------

// Init: yp = pad(relu(conv3x3(x, W_ff, pad1))); also zero e_sq[0..511].
__global__ __launch_bounds__(256) void k_init(const float* __restrict__ x,
                                              const float* __restrict__ Wff,
                                              float* __restrict__ yp,
                                              float* __restrict__ e_sq) {
  __shared__ __align__(16) float sA[34 * PITCH];
  __shared__ __align__(16) float sB[34 * PITCH];
  int tid = threadIdx.x;
  int b = blockIdx.x >> 7, c = blockIdx.x & 127;
  if (blockIdx.x == 0) {
    for (int i = tid; i < 512; i += 256) e_sq[i] = 0.f;
  }
  for (int i = tid; i < 34 * PITCH; i += 256) { sA[i] = 0.f; sB[i] = 0.f; }
  __syncthreads();
  int y = tid >> 3, x0 = (tid & 7) * 4;
  float acc[4] = {0.f, 0.f, 0.f, 0.f};
  const float* xb = x + (size_t)(b * CIN) * NPIX;
  stage_x(xb, sA, tid);
  __syncthreads();
  for (int ci = 0; ci < CIN; ci += 2) {
    stage_x(xb + (size_t)(ci + 1) * NPIX, sB, tid);
    conv_acc(sA, Wff + (size_t)(c * CIN + ci) * 9, y, x0, acc);
    __syncthreads();
    if (ci + 2 < CIN) stage_x(xb + (size_t)(ci + 2) * NPIX, sA, tid);
    conv_acc(sB, Wff + (size_t)(c * CIN + ci + 1) * 9, y, x0, acc);
    __syncthreads();
  }
  float* ypp = yp + (size_t)(b * COUT + c) * YP_PLANE;
  for (int i = tid; i < YP_PLANE; i += 256) {
    int p = i / 34, q = i - p * 34;
    if (p == 0 || p == 33 || q == 0 || q == 33) ypp[i] = 0.f;
  }
#pragma unroll
  for (int k = 0; k < 4; ++k) {
    float v = acc[k] > 0.f ? acc[k] : 0.f;
    ypp[(y + 1) * 34 + (x0 + 1 + k)] = v;
  }
}

// Forward: r = x - conv_valid(yp, Wfb[c][o]); atomicAdd block sum of r^2 into e_slot.
// grid: 256 blocks = (b<<6)|o, o = x-channel (0..63)
__global__ __launch_bounds__(256) void k_forward(const float* __restrict__ x,
                                                 const float* __restrict__ Wfb,
                                                 const float* __restrict__ yp,
                                                 float* __restrict__ r,
                                                 float* __restrict__ e_slot) {
  __shared__ __align__(16) float sA[34 * PITCH];
  __shared__ __align__(16) float sB[34 * PITCH];
  __shared__ float wsum[4];
  int tid = threadIdx.x;
  int b = blockIdx.x >> 6, o = blockIdx.x & 63;
  int y = tid >> 3, x0 = (tid & 7) * 4;
  float acc[4] = {0.f, 0.f, 0.f, 0.f};
  const float* ypb = yp + (size_t)(b * COUT) * YP_PLANE;
  stage_plane34(ypb, sA, tid);
  __syncthreads();
  for (int c = 0; c < COUT; c += 2) {
    stage_plane34(ypb + (size_t)(c + 1) * YP_PLANE, sB, tid);
    conv_acc(sA, Wfb + (size_t)(c * CIN + o) * 9, y, x0, acc);
    __syncthreads();
    if (c + 2 < COUT) stage_plane34(ypb + (size_t)(c + 2) * YP_PLANE, sA, tid);
    conv_acc(sB, Wfb + (size_t)((c + 1) * CIN + o) * 9, y, x0, acc);
    __syncthreads();
  }
  size_t off = (size_t)(b * CIN + o) * NPIX + y * 32 + x0;
  float4 xv = *(const float4*)(x + off);
  float r0 = xv.x - acc[0], r1 = xv.y - acc[1], r2 = xv.z - acc[2], r3 = xv.w - acc[3];
  float4 rv = {r0, r1, r2, r3};
  *(float4*)(r + off) = rv;
  float ss = r0 * r0 + r1 * r1 + r2 * r2 + r3 * r3;
#pragma unroll
  for (int d = 32; d; d >>= 1) ss += __shfl_down(ss, d, 64);
  if ((tid & 63) == 0) wsum[tid >> 6] = ss;
  __syncthreads();
  if (tid == 0) atomicAdd(e_slot, wsum[0] + wsum[1] + wsum[2] + wsum[3]);
}

// Update: yp[b,c] += (LR/e) * full-corr(r[b,:], Wfb[c,:]).
// grid: 512 blocks = (b<<7)|c, c = yp channel (0..127)
__global__ __launch_bounds__(256) void k_update(const float* __restrict__ r,
                                                const float* __restrict__ Wfb,
                                                float* __restrict__ yp,
                                                const float* __restrict__ e_slot) {
  __shared__ __align__(16) float sA[36 * UPITCH];
  __shared__ __align__(16) float sB[36 * UPITCH];
  int tid = threadIdx.x;
  int b = blockIdx.x >> 7, c = blockIdx.x & 127;
  float e = sqrtf(*e_slot);
  float scale = LR_F / e;
  for (int i = tid; i < 36 * UPITCH; i += 256) { sA[i] = 0.f; sB[i] = 0.f; }
  __syncthreads();
  // tasks: 34 rows x 9 col-groups(4) over 36 virtual cols = 306 tasks
  int t0 = tid, t1 = tid + 256;
  int p0 = t0 / 9, q0 = (t0 - p0 * 9) * 4;
  int p1t = t1 / 9, q1 = (t1 - p1t * 9) * 4;
  bool has1 = (t1 < 306);
  int p1 = has1 ? p1t : 0;
  float a0[4] = {0.f, 0.f, 0.f, 0.f}, a1[4] = {0.f, 0.f, 0.f, 0.f};
  const float* rb = r + (size_t)(b * CIN) * NPIX;
  stage_r(rb, sA, tid);
  __syncthreads();
  for (int o = 0; o < CIN; o += 2) {
    stage_r(rb + (size_t)(o + 1) * NPIX, sB, tid);
    {
      const float* w9 = Wfb + (size_t)(c * CIN + o) * 9;
      tconv_acc(sA, w9, p0, q0, a0);
      if (has1) tconv_acc(sA, w9, p1, q1, a1);
    }
    __syncthreads();
    if (o + 2 < CIN) stage_r(rb + (size_t)(o + 2) * NPIX, sA, tid);
    {
      const float* w9 = Wfb + (size_t)(c * CIN + o + 1) * 9;
      tconv_acc(sB, w9, p0, q0, a0);
      if (has1) tconv_acc(sB, w9, p1, q1, a1);
    }
    __syncthreads();
  }
  float* ypp = yp + (size_t)(b * COUT + c) * YP_PLANE;
#pragma unroll
  for (int k = 0; k < 4; ++k) {
    int q = q0 + k;
    if (q < 34) ypp[p0 * 34 + q] += scale * a0[k];
  }
  if (has1) {
#pragma unroll
    for (int k = 0; k < 4; ++k) {
      int q = q1 + k;
      if (q < 34) ypp[p1 * 34 + q] += scale * a1[k];
    }
  }
}

// Final: out = yp interior + conv1x1(x, W_bypass). grid: 512 = (b<<7)|o
__global__ __launch_bounds__(256) void k_final(const float* __restrict__ x,
                                               const float* __restrict__ Wb,
                                               const float* __restrict__ yp,
                                               float* __restrict__ out) {
  int tid = threadIdx.x;
  int b = blockIdx.x >> 7, o = blockIdx.x & 127;
  int y = tid >> 3, x0 = (tid & 7) * 4;
  const float* ypp = yp + (size_t)(b * COUT + o) * YP_PLANE + (y + 1) * 34 + (x0 + 1);
  float acc[4] = {ypp[0], ypp[1], ypp[2], ypp[3]};
  const float* xb = x + (size_t)(b * CIN) * NPIX + y * 32 + x0;
  const float* wb = Wb + o * CIN;
  for (int ci = 0; ci < CIN; ++ci) {
    float4 xv = *(const float4*)(xb + (size_t)ci * NPIX);
    float wv = wb[ci];
    acc[0] = fmaf(xv.x, wv, acc[0]);
    acc[1] = fmaf(xv.y, wv, acc[1]);
    acc[2] = fmaf(xv.z, wv, acc[2]);
    acc[3] = fmaf(xv.w, wv, acc[3]);
  }
  float4 ov = {acc[0], acc[1], acc[2], acc[3]};
  *(float4*)(out + (size_t)(b * COUT + o) * NPIX + y * 32 + x0) = ov;
}

// ---- launch -----------------------------------------------------------------

extern "C" void kernel_launch(void* const* d_in, const int* in_sizes, int n_in,
                              void* d_out, int out_size, void* d_ws, size_t ws_size,
                              hipStream_t stream) {
  const float* x   = (const float*)d_in[0];
  const float* Wff = (const float*)d_in[1];
  const float* Wfb = (const float*)d_in[2];
  const float* Wb  = (const float*)d_in[3];
  float* out = (float*)d_out;

  float* yp   = (float*)d_ws;                        // 4*128*1156 = 591872 floats
  float* r    = yp + (size_t)4 * COUT * YP_PLANE;    // 4*64*1024  = 262144 floats
  float* e_sq = r + (size_t)4 * CIN * NPIX;          // 512 floats

  hipLaunchKernelGGL(k_init, dim3(512), dim3(256), 0, stream, x, Wff, yp, e_sq);
  for (int t = 0; t < NUM_ITERS; ++t) {
    hipLaunchKernelGGL(k_forward, dim3(256), dim3(256), 0, stream, x, Wfb, yp, r, e_sq + t);
    hipLaunchKernelGGL(k_update, dim3(512), dim3(256), 0, stream, r, Wfb, yp, e_sq + t);
  }
  hipLaunchKernelGGL(k_final, dim3(512), dim3(256), 0, stream, x, Wb, yp, out);
}

// Round 2
// 23594.429 us; speedup vs baseline: 3.0620x; 3.0620x over previous
//
#include <hip/hip_runtime.h>

#define CIN 64
#define COUT 128
#define NPIX 1024        // 32*32
#define YP_PLANE 1156    // 34*34
#define PITCH 36         // LDS pitch for 34-wide planes
#define NUM_ITERS 500
#define LR_F 0.001f

// ---- helpers ----------------------------------------------------------------

// Stage a 34x34 plane (contiguous 1156 floats, 16B-aligned) into pitch-36 LDS.
__device__ __forceinline__ void stage_plane34(const float* __restrict__ g, float* s, int tid) {
  for (int i4 = tid; i4 < 289; i4 += 256) {   // 289 float4 = 1156 floats
    float4 v = ((const float4*)g)[i4];
    int e = i4 * 4;
    int ry = e / 34, rx = e - ry * 34;
    float vv[4] = {v.x, v.y, v.z, v.w};
#pragma unroll
    for (int k = 0; k < 4; ++k) {
      s[ry * PITCH + rx] = vv[k];
      if (++rx == 34) { rx = 0; ++ry; }
    }
  }
}

// Stage a 32x32 plane into pitch-36 LDS at offset (+1,+1); border stays zero.
__device__ __forceinline__ void stage_x(const float* __restrict__ g, float* s, int tid) {
  int ry = tid >> 3, rx = (tid & 7) * 4;
  float4 v = *(const float4*)(g + ry * 32 + rx);
  float* d = s + (ry + 1) * PITCH + rx + 1;
  d[0] = v.x; d[1] = v.y; d[2] = v.z; d[3] = v.w;
}

// acc[k] += sum_{di,dj} s[(y+di)*PITCH + x0+k+dj] * w9[di*3+dj], k=0..3
__device__ __forceinline__ void conv_acc(const float* s, const float* __restrict__ w9,
                                         int y, int x0, float acc[4]) {
  float w[9];
#pragma unroll
  for (int i = 0; i < 9; ++i) w[i] = w9[i];
#pragma unroll
  for (int di = 0; di < 3; ++di) {
    const float* row = s + (y + di) * PITCH + x0;
    float4 v4 = *(const float4*)row;
    float2 v2 = *(const float2*)(row + 4);
    float v[6] = {v4.x, v4.y, v4.z, v4.w, v2.x, v2.y};
#pragma unroll
    for (int dj = 0; dj < 3; ++dj) {
      float wv = w[di * 3 + dj];
#pragma unroll
      for (int k = 0; k < 4; ++k) acc[k] = fmaf(v[k + dj], wv, acc[k]);
    }
  }
}

// load 25 (padded 28) weights for (och,o) from G row (stride 32, 16B aligned)
__device__ __forceinline__ void wload(const float* __restrict__ gb, int o, float w[28]) {
  const float4* g4 = (const float4*)(gb + o * 32);
#pragma unroll
  for (int i = 0; i < 7; ++i) {
    float4 v = g4[i];
    w[4 * i] = v.x; w[4 * i + 1] = v.y; w[4 * i + 2] = v.z; w[4 * i + 3] = v.w;
  }
}

// 5x5 conv tap loop: acc{0,1} for out cols cg*2 + {0,1}
__device__ __forceinline__ void conv5(const float* sbuf, int row_l, int cg, const float w[28],
                                      float& acc0, float& acc1) {
#pragma unroll
  for (int wr = 0; wr < 5; ++wr) {
    const float* rp = sbuf + (row_l + wr) * 40 + cg * 2 + 2;
    float2 p0 = *(const float2*)rp;
    float2 p1 = *(const float2*)(rp + 2);
    float2 p2 = *(const float2*)(rp + 4);
    float v[6] = {p0.x, p0.y, p1.x, p1.y, p2.x, p2.y};
#pragma unroll
    for (int vc = 0; vc < 5; ++vc) {
      acc0 = fmaf(w[wr * 5 + vc], v[vc], acc0);
      acc1 = fmaf(w[wr * 5 + vc], v[vc + 1], acc1);
    }
  }
}

// ---- kernels ----------------------------------------------------------------

// Init: yp0 = pad(relu(conv3x3(x, W_ff, pad1))); zero e_sq[0..511]; zero s.
__global__ __launch_bounds__(256) void k_init(const float* __restrict__ x,
                                              const float* __restrict__ Wff,
                                              float* __restrict__ yp,
                                              float* __restrict__ e_sq,
                                              float* __restrict__ s_clr) {
  __shared__ __align__(16) float sA[34 * PITCH];
  __shared__ __align__(16) float sB[34 * PITCH];
  int tid = threadIdx.x;
  int b = blockIdx.x >> 7, c = blockIdx.x & 127;
  if (blockIdx.x == 0) {
    for (int i = tid; i < 512; i += 256) e_sq[i] = 0.f;
  }
  // zero s: 262144 floats over 512 blocks
  for (int i = tid; i < 512; i += 256) s_clr[(size_t)blockIdx.x * 512 + i] = 0.f;
  for (int i = tid; i < 34 * PITCH; i += 256) { sA[i] = 0.f; sB[i] = 0.f; }
  __syncthreads();
  int y = tid >> 3, x0 = (tid & 7) * 4;
  float acc[4] = {0.f, 0.f, 0.f, 0.f};
  const float* xb = x + (size_t)(b * CIN) * NPIX;
  stage_x(xb, sA, tid);
  __syncthreads();
  for (int ci = 0; ci < CIN; ci += 2) {
    stage_x(xb + (size_t)(ci + 1) * NPIX, sB, tid);
    conv_acc(sA, Wff + (size_t)(c * CIN + ci) * 9, y, x0, acc);
    __syncthreads();
    if (ci + 2 < CIN) stage_x(xb + (size_t)(ci + 2) * NPIX, sA, tid);
    conv_acc(sB, Wff + (size_t)(c * CIN + ci + 1) * 9, y, x0, acc);
    __syncthreads();
  }
  float* ypp = yp + (size_t)(b * COUT + c) * YP_PLANE;
  for (int i = tid; i < YP_PLANE; i += 256) {
    int p = i / 34, q = i - p * 34;
    if (p == 0 || p == 33 || q == 0 || q == 33) ypp[i] = 0.f;
  }
#pragma unroll
  for (int k = 0; k < 4; ++k) {
    float v = acc[k] > 0.f ? acc[k] : 0.f;
    ypp[(y + 1) * 34 + (x0 + 1 + k)] = v;
  }
}

// Gram: G[o'*64+o][tap] (tap=(u+2)*5+(v+2), row stride 32)
//   = sum_c sum_{ei,ej} Wfb[c,o',ei,ej] * Wfb[c,o,ei-u,ej-v]
__global__ __launch_bounds__(256) void k_gram(const float* __restrict__ Wfb,
                                              float* __restrict__ G) {
  __shared__ float wA[128 * 9];
  __shared__ float gred[256][25];
  int tid = threadIdx.x;
  int op = blockIdx.x;  // o' in [0,64)
  for (int i = tid; i < 1152; i += 256) {
    int c = i / 9, k = i - c * 9;
    wA[i] = Wfb[(size_t)(c * 64 + op) * 9 + k];
  }
  __syncthreads();
  int o = tid & 63, part = tid >> 6;
  float g[25];
#pragma unroll
  for (int i = 0; i < 25; ++i) g[i] = 0.f;
  for (int c = part * 32; c < part * 32 + 32; ++c) {
    float b9[9];
#pragma unroll
    for (int k = 0; k < 9; ++k) b9[k] = Wfb[(size_t)(c * 64 + o) * 9 + k];
    const float* a9 = &wA[c * 9];
#pragma unroll
    for (int ei = 0; ei < 3; ++ei)
#pragma unroll
      for (int ej = 0; ej < 3; ++ej) {
        float av = a9[ei * 3 + ej];
#pragma unroll
        for (int di = 0; di < 3; ++di)
#pragma unroll
          for (int dj = 0; dj < 3; ++dj)
            g[(ei - di + 2) * 5 + (ej - dj + 2)] = fmaf(av, b9[di * 3 + dj],
                                                        g[(ei - di + 2) * 5 + (ej - dj + 2)]);
      }
  }
#pragma unroll
  for (int i = 0; i < 25; ++i) gred[tid][i] = g[i];
  __syncthreads();
  if (part == 0) {
    float* dst = G + ((size_t)op * 64 + o) * 32;
#pragma unroll
    for (int i = 0; i < 25; ++i)
      dst[i] = gred[tid][i] + gred[tid + 64][i] + gred[tid + 128][i] + gred[tid + 192][i];
  }
}

// r0 = x - conv_valid(yp0, Wfb[c][o]); atomicAdd block sum of r^2 into e_slot.
// grid: 256 blocks = (b<<6)|o
__global__ __launch_bounds__(256) void k_forward(const float* __restrict__ x,
                                                 const float* __restrict__ Wfb,
                                                 const float* __restrict__ yp,
                                                 float* __restrict__ r,
                                                 float* __restrict__ e_slot) {
  __shared__ __align__(16) float sA[34 * PITCH];
  __shared__ __align__(16) float sB[34 * PITCH];
  __shared__ float wsum[4];
  int tid = threadIdx.x;
  int b = blockIdx.x >> 6, o = blockIdx.x & 63;
  int y = tid >> 3, x0 = (tid & 7) * 4;
  float acc[4] = {0.f, 0.f, 0.f, 0.f};
  const float* ypb = yp + (size_t)(b * COUT) * YP_PLANE;
  stage_plane34(ypb, sA, tid);
  __syncthreads();
  for (int c = 0; c < COUT; c += 2) {
    stage_plane34(ypb + (size_t)(c + 1) * YP_PLANE, sB, tid);
    conv_acc(sA, Wfb + (size_t)(c * CIN + o) * 9, y, x0, acc);
    __syncthreads();
    if (c + 2 < COUT) stage_plane34(ypb + (size_t)(c + 2) * YP_PLANE, sA, tid);
    conv_acc(sB, Wfb + (size_t)((c + 1) * CIN + o) * 9, y, x0, acc);
    __syncthreads();
  }
  size_t off = (size_t)(b * CIN + o) * NPIX + y * 32 + x0;
  float4 xv = *(const float4*)(x + off);
  float r0 = xv.x - acc[0], r1 = xv.y - acc[1], r2 = xv.z - acc[2], r3 = xv.w - acc[3];
  float4 rv = {r0, r1, r2, r3};
  *(float4*)(r + off) = rv;
  float ss = r0 * r0 + r1 * r1 + r2 * r2 + r3 * r3;
#pragma unroll
  for (int d = 32; d; d >>= 1) ss += __shfl_down(ss, d, 64);
  if ((tid & 63) == 0) wsum[tid >> 6] = ss;
  __syncthreads();
  if (tid == 0) atomicAdd(e_slot, wsum[0] + wsum[1] + wsum[2] + wsum[3]);
}

// One SGD step in r-space:
//   alpha = LR/sqrt(e_in);  s += alpha*r_t;  r_{t+1} = r_t - alpha*(G (*) r_t)
//   e_out += ||r_{t+1}||^2 (block partial)
// grid: 512 blocks = b(2) | och_t(4b->16) | row_t(3b->8). Block owns 4 och x 4 rows x 32 cols.
// thread: wave = och_local (wave-uniform), row_l = (tid>>4)&3, cg = tid&15 (2 cols).
__global__ __launch_bounds__(256) void k_iter(const float* __restrict__ rin,
                                              float* __restrict__ rout,
                                              float* __restrict__ s,
                                              const float* __restrict__ G,
                                              const float* __restrict__ e_in,
                                              float* __restrict__ e_out) {
  __shared__ __align__(16) float sIn[2][8 * 40];
  __shared__ float wsum[4];
  int tid = threadIdx.x;
  int blk = blockIdx.x;
  int b = blk >> 7, och_t = (blk >> 3) & 15, row_t = blk & 7;
  int wv = __builtin_amdgcn_readfirstlane(tid >> 6);   // wave id, uniform
  int och = och_t * 4 + wv;                            // global out channel
  int row_l = (tid >> 4) & 3;
  int cg = tid & 15;

  // zero both LDS buffers (halo cols/rows persist as zero)
  for (int i = tid; i < 2 * 320; i += 256) ((float*)sIn)[i] = 0.f;

  // phase 1: alpha, s += alpha*r (own 2 pixels)
  float alpha = LR_F / sqrtf(*e_in);
  int gi = row_t * 4 + row_l;
  size_t own = ((size_t)(b * 64 + och) * 32 + gi) * 32 + cg * 2;
  float2 rv = *(const float2*)(rin + own);
  float2 sv = *(const float2*)(s + own);
  sv.x = fmaf(alpha, rv.x, sv.x);
  sv.y = fmaf(alpha, rv.y, sv.y);
  *(float2*)(s + own) = sv;

  // staging setup: 64 tasks spread over all 4 waves ((tid&3)==0 active)
  bool stager = ((tid & 3) == 0);
  int task = tid >> 2;
  int srow = task >> 3, scg = task & 7;
  int gr = row_t * 4 - 2 + srow;
  bool srv = stager && gr >= 0 && gr < 32;
  const float* rbase = rin + ((long)(b * 64) * NPIX + (long)gr * 32 + scg * 4);
  float* sdst = &sIn[0][srow * 40 + 4 + scg * 4];

  const float* gb = G + (size_t)och * 64 * 32;
  float wA[28], wB[28];
  float acc0 = 0.f, acc1 = 0.f;
  float4 stg;

  if (srv) stg = *(const float4*)(rbase);              // plane 0
  wload(gb, 0, wA);
  __syncthreads();                                     // LDS zeroing done
  if (srv) *(float4*)(sdst) = stg;
  __syncthreads();

  for (int o = 0; o < 64; o += 2) {
    // body A: compute plane o from buf0/wA; prefetch o+1 into buf1/wB
    if (srv) stg = *(const float4*)(rbase + (size_t)(o + 1) * NPIX);
    wload(gb, o + 1, wB);
    conv5(sIn[0], row_l, cg, wA, acc0, acc1);
    if (srv) *(float4*)(sdst + 320) = stg;
    __syncthreads();
    // body B: compute plane o+1 from buf1/wB; prefetch o+2 into buf0/wA
    bool more = (o + 2 < 64);
    if (more) {
      if (srv) stg = *(const float4*)(rbase + (size_t)(o + 2) * NPIX);
      wload(gb, o + 2, wA);
    }
    conv5(sIn[1], row_l, cg, wB, acc0, acc1);
    if (more && srv) *(float4*)(sdst) = stg;
    __syncthreads();
  }

  // r_{t+1} = r_t - alpha * acc
  float rn0 = fmaf(-alpha, acc0, rv.x);
  float rn1 = fmaf(-alpha, acc1, rv.y);
  float2 rn = {rn0, rn1};
  *(float2*)(rout + own) = rn;
  float ss = rn0 * rn0 + rn1 * rn1;
#pragma unroll
  for (int d = 32; d; d >>= 1) ss += __shfl_down(ss, d, 64);
  if ((tid & 63) == 0) wsum[tid >> 6] = ss;
  __syncthreads();
  if (tid == 0) atomicAdd(e_out, wsum[0] + wsum[1] + wsum[2] + wsum[3]);
}

// out = yp0_interior + (A^T s)_interior + conv1x1(x, W_bypass). grid: 512 = (b<<7)|co
__global__ __launch_bounds__(256) void k_finalize(const float* __restrict__ x,
                                                  const float* __restrict__ Wfb,
                                                  const float* __restrict__ Wb,
                                                  const float* __restrict__ yp0,
                                                  const float* __restrict__ s,
                                                  float* __restrict__ out) {
  __shared__ __align__(16) float sA[34 * PITCH];
  __shared__ __align__(16) float sB[34 * PITCH];
  int tid = threadIdx.x;
  int b = blockIdx.x >> 7, co = blockIdx.x & 127;
  for (int i = tid; i < 34 * PITCH; i += 256) { sA[i] = 0.f; sB[i] = 0.f; }
  __syncthreads();
  int y = tid >> 3, x0 = (tid & 7) * 4;
  float acc[4] = {0.f, 0.f, 0.f, 0.f};
  const float* sb = s + (size_t)(b * 64) * NPIX;
  stage_x(sb, sA, tid);
  __syncthreads();
  for (int o = 0; o < 64; o += 2) {
    stage_x(sb + (size_t)(o + 1) * NPIX, sB, tid);
    {
      const float* wg = Wfb + (size_t)(co * 64 + o) * 9;
      float wf[9];
#pragma unroll
      for (int i = 0; i < 9; ++i) wf[i] = wg[8 - i];   // flipped 3x3
      conv_acc(sA, wf, y, x0, acc);
    }
    __syncthreads();
    if (o + 2 < 64) stage_x(sb + (size_t)(o + 2) * NPIX, sA, tid);
    {
      const float* wg = Wfb + (size_t)(co * 64 + o + 1) * 9;
      float wf[9];
#pragma unroll
      for (int i = 0; i < 9; ++i) wf[i] = wg[8 - i];
      conv_acc(sB, wf, y, x0, acc);
    }
    __syncthreads();
  }
  // bypass 1x1 over x
  const float* xb = x + (size_t)(b * 64) * NPIX + y * 32 + x0;
  const float* wbp = Wb + co * 64;
  for (int ci = 0; ci < 64; ++ci) {
    float4 xv = *(const float4*)(xb + (size_t)ci * NPIX);
    float wvv = wbp[ci];
    acc[0] = fmaf(xv.x, wvv, acc[0]);
    acc[1] = fmaf(xv.y, wvv, acc[1]);
    acc[2] = fmaf(xv.z, wvv, acc[2]);
    acc[3] = fmaf(xv.w, wvv, acc[3]);
  }
  const float* ypp = yp0 + (size_t)(b * COUT + co) * YP_PLANE + (y + 1) * 34 + (x0 + 1);
  float4 ov = {acc[0] + ypp[0], acc[1] + ypp[1], acc[2] + ypp[2], acc[3] + ypp[3]};
  *(float4*)(out + (size_t)(b * COUT + co) * NPIX + y * 32 + x0) = ov;
}

// ---- launch -----------------------------------------------------------------

extern "C" void kernel_launch(void* const* d_in, const int* in_sizes, int n_in,
                              void* d_out, int out_size, void* d_ws, size_t ws_size,
                              hipStream_t stream) {
  const float* x   = (const float*)d_in[0];
  const float* Wff = (const float*)d_in[1];
  const float* Wfb = (const float*)d_in[2];
  const float* Wb  = (const float*)d_in[3];
  float* out = (float*)d_out;

  float* yp0  = (float*)d_ws;                          // 591872 floats
  float* rA   = yp0 + (size_t)4 * COUT * YP_PLANE;     // 262144
  float* rB   = rA + (size_t)4 * CIN * NPIX;           // 262144
  float* s    = rB + (size_t)4 * CIN * NPIX;           // 262144
  float* G    = s  + (size_t)4 * CIN * NPIX;           // 131072 (64*64*32)
  float* e_sq = G  + (size_t)64 * 64 * 32;             // 512

  hipLaunchKernelGGL(k_init,    dim3(512), dim3(256), 0, stream, x, Wff, yp0, e_sq, s);
  hipLaunchKernelGGL(k_gram,    dim3(64),  dim3(256), 0, stream, Wfb, G);
  hipLaunchKernelGGL(k_forward, dim3(256), dim3(256), 0, stream, x, Wfb, yp0, rA, e_sq);

  float* rc = rA;
  float* rn = rB;
  for (int t = 0; t < NUM_ITERS; ++t) {
    hipLaunchKernelGGL(k_iter, dim3(512), dim3(256), 0, stream, rc, rn, s, G,
                       e_sq + t, e_sq + t + 1);
    float* tmp = rc; rc = rn; rn = tmp;
  }
  hipLaunchKernelGGL(k_finalize, dim3(512), dim3(256), 0, stream, x, Wfb, Wb, yp0, s, out);
}

// Round 3
// 703.715 us; speedup vs baseline: 102.6648x; 33.5284x over previous
//
#include <hip/hip_runtime.h>

#define CIN 64
#define COUT 128
#define NPIX 1024        // 32*32
#define YP_PLANE 1156    // 34*34
#define PITCH 36         // LDS pitch for 34-wide planes
#define NUM_ITERS 500
#define LR_F 0.001f
#define KRYLOV 8
#define VPLANE 262144    // 4*64*1024 floats per Krylov vector

// ---- helpers ----------------------------------------------------------------

// Stage a 34x34 plane (contiguous 1156 floats, 16B-aligned) into pitch-36 LDS.
__device__ __forceinline__ void stage_plane34(const float* __restrict__ g, float* s, int tid) {
  for (int i4 = tid; i4 < 289; i4 += 256) {   // 289 float4 = 1156 floats
    float4 v = ((const float4*)g)[i4];
    int e = i4 * 4;
    int ry = e / 34, rx = e - ry * 34;
    float vv[4] = {v.x, v.y, v.z, v.w};
#pragma unroll
    for (int k = 0; k < 4; ++k) {
      s[ry * PITCH + rx] = vv[k];
      if (++rx == 34) { rx = 0; ++ry; }
    }
  }
}

// Stage a 32x32 plane into pitch-36 LDS at offset (+1,+1); border stays zero.
__device__ __forceinline__ void stage_x(const float* __restrict__ g, float* s, int tid) {
  int ry = tid >> 3, rx = (tid & 7) * 4;
  float4 v = *(const float4*)(g + ry * 32 + rx);
  float* d = s + (ry + 1) * PITCH + rx + 1;
  d[0] = v.x; d[1] = v.y; d[2] = v.z; d[3] = v.w;
}

// acc[k] += sum_{di,dj} s[(y+di)*PITCH + x0+k+dj] * w9[di*3+dj], k=0..3
__device__ __forceinline__ void conv_acc(const float* s, const float* __restrict__ w9,
                                         int y, int x0, float acc[4]) {
  float w[9];
#pragma unroll
  for (int i = 0; i < 9; ++i) w[i] = w9[i];
#pragma unroll
  for (int di = 0; di < 3; ++di) {
    const float* row = s + (y + di) * PITCH + x0;
    float4 v4 = *(const float4*)row;
    float2 v2 = *(const float2*)(row + 4);
    float v[6] = {v4.x, v4.y, v4.z, v4.w, v2.x, v2.y};
#pragma unroll
    for (int dj = 0; dj < 3; ++dj) {
      float wv = w[di * 3 + dj];
#pragma unroll
      for (int k = 0; k < 4; ++k) acc[k] = fmaf(v[k + dj], wv, acc[k]);
    }
  }
}

// load 25 (padded 28) weights for (och,o) from G row (stride 32, 16B aligned)
__device__ __forceinline__ void wload(const float* __restrict__ gb, int o, float w[28]) {
  const float4* g4 = (const float4*)(gb + o * 32);
#pragma unroll
  for (int i = 0; i < 7; ++i) {
    float4 v = g4[i];
    w[4 * i] = v.x; w[4 * i + 1] = v.y; w[4 * i + 2] = v.z; w[4 * i + 3] = v.w;
  }
}

// 5x5 conv tap loop: acc{0,1} for out cols cg*2 + {0,1}
__device__ __forceinline__ void conv5(const float* sbuf, int row_l, int cg, const float w[28],
                                      float& acc0, float& acc1) {
#pragma unroll
  for (int wr = 0; wr < 5; ++wr) {
    const float* rp = sbuf + (row_l + wr) * 40 + cg * 2 + 2;
    float2 p0 = *(const float2*)rp;
    float2 p1 = *(const float2*)(rp + 2);
    float2 p2 = *(const float2*)(rp + 4);
    float v[6] = {p0.x, p0.y, p1.x, p1.y, p2.x, p2.y};
#pragma unroll
    for (int vc = 0; vc < 5; ++vc) {
      acc0 = fmaf(w[wr * 5 + vc], v[vc], acc0);
      acc1 = fmaf(w[wr * 5 + vc], v[vc + 1], acc1);
    }
  }
}

// ---- kernels ----------------------------------------------------------------

// Init: yp0 = pad(relu(conv3x3(x, W_ff, pad1))); block 0 zeroes Gamma[64].
__global__ __launch_bounds__(256) void k_init(const float* __restrict__ x,
                                              const float* __restrict__ Wff,
                                              float* __restrict__ yp,
                                              float* __restrict__ Gam) {
  __shared__ __align__(16) float sA[34 * PITCH];
  __shared__ __align__(16) float sB[34 * PITCH];
  int tid = threadIdx.x;
  int b = blockIdx.x >> 7, c = blockIdx.x & 127;
  if (blockIdx.x == 0 && tid < 64) Gam[tid] = 0.f;
  for (int i = tid; i < 34 * PITCH; i += 256) { sA[i] = 0.f; sB[i] = 0.f; }
  __syncthreads();
  int y = tid >> 3, x0 = (tid & 7) * 4;
  float acc[4] = {0.f, 0.f, 0.f, 0.f};
  const float* xb = x + (size_t)(b * CIN) * NPIX;
  stage_x(xb, sA, tid);
  __syncthreads();
  for (int ci = 0; ci < CIN; ci += 2) {
    stage_x(xb + (size_t)(ci + 1) * NPIX, sB, tid);
    conv_acc(sA, Wff + (size_t)(c * CIN + ci) * 9, y, x0, acc);
    __syncthreads();
    if (ci + 2 < CIN) stage_x(xb + (size_t)(ci + 2) * NPIX, sA, tid);
    conv_acc(sB, Wff + (size_t)(c * CIN + ci + 1) * 9, y, x0, acc);
    __syncthreads();
  }
  float* ypp = yp + (size_t)(b * COUT + c) * YP_PLANE;
  for (int i = tid; i < YP_PLANE; i += 256) {
    int p = i / 34, q = i - p * 34;
    if (p == 0 || p == 33 || q == 0 || q == 33) ypp[i] = 0.f;
  }
#pragma unroll
  for (int k = 0; k < 4; ++k) {
    float v = acc[k] > 0.f ? acc[k] : 0.f;
    ypp[(y + 1) * 34 + (x0 + 1 + k)] = v;
  }
}

// Gram conv kernel: G[o'*64+o][tap] (tap=(u+2)*5+(v+2), row stride 32)
//   = sum_c sum_{ei,ej} Wfb[c,o',ei,ej] * Wfb[c,o,ei-u,ej-v]
__global__ __launch_bounds__(256) void k_gram(const float* __restrict__ Wfb,
                                              float* __restrict__ G) {
  __shared__ float wA[128 * 9];
  __shared__ float gred[256][25];
  int tid = threadIdx.x;
  int op = blockIdx.x;  // o' in [0,64)
  for (int i = tid; i < 1152; i += 256) {
    int c = i / 9, k = i - c * 9;
    wA[i] = Wfb[(size_t)(c * 64 + op) * 9 + k];
  }
  __syncthreads();
  int o = tid & 63, part = tid >> 6;
  float g[25];
#pragma unroll
  for (int i = 0; i < 25; ++i) g[i] = 0.f;
  for (int c = part * 32; c < part * 32 + 32; ++c) {
    float b9[9];
#pragma unroll
    for (int k = 0; k < 9; ++k) b9[k] = Wfb[(size_t)(c * 64 + o) * 9 + k];
    const float* a9 = &wA[c * 9];
#pragma unroll
    for (int ei = 0; ei < 3; ++ei)
#pragma unroll
      for (int ej = 0; ej < 3; ++ej) {
        float av = a9[ei * 3 + ej];
#pragma unroll
        for (int di = 0; di < 3; ++di)
#pragma unroll
          for (int dj = 0; dj < 3; ++dj)
            g[(ei - di + 2) * 5 + (ej - dj + 2)] = fmaf(av, b9[di * 3 + dj],
                                                        g[(ei - di + 2) * 5 + (ej - dj + 2)]);
      }
  }
#pragma unroll
  for (int i = 0; i < 25; ++i) gred[tid][i] = g[i];
  __syncthreads();
  if (part == 0) {
    float* dst = G + ((size_t)op * 64 + o) * 32;
#pragma unroll
    for (int i = 0; i < 25; ++i)
      dst[i] = gred[tid][i] + gred[tid + 64][i] + gred[tid + 128][i] + gred[tid + 192][i];
  }
}

// v0 = r0 = x - conv_valid(yp0, Wfb[c][o]). grid: 256 blocks = (b<<6)|o
__global__ __launch_bounds__(256) void k_forward(const float* __restrict__ x,
                                                 const float* __restrict__ Wfb,
                                                 const float* __restrict__ yp,
                                                 float* __restrict__ v0) {
  __shared__ __align__(16) float sA[34 * PITCH];
  __shared__ __align__(16) float sB[34 * PITCH];
  int tid = threadIdx.x;
  int b = blockIdx.x >> 6, o = blockIdx.x & 63;
  int y = tid >> 3, x0 = (tid & 7) * 4;
  float acc[4] = {0.f, 0.f, 0.f, 0.f};
  const float* ypb = yp + (size_t)(b * COUT) * YP_PLANE;
  stage_plane34(ypb, sA, tid);
  __syncthreads();
  for (int c = 0; c < COUT; c += 2) {
    stage_plane34(ypb + (size_t)(c + 1) * YP_PLANE, sB, tid);
    conv_acc(sA, Wfb + (size_t)(c * CIN + o) * 9, y, x0, acc);
    __syncthreads();
    if (c + 2 < COUT) stage_plane34(ypb + (size_t)(c + 2) * YP_PLANE, sA, tid);
    conv_acc(sB, Wfb + (size_t)((c + 1) * CIN + o) * 9, y, x0, acc);
    __syncthreads();
  }
  size_t off = (size_t)(b * CIN + o) * NPIX + y * 32 + x0;
  float4 xv = *(const float4*)(x + off);
  float4 rv = {xv.x - acc[0], xv.y - acc[1], xv.z - acc[2], xv.w - acc[3]};
  *(float4*)(v0 + off) = rv;
}

// v_{j+1} = G (*) v_j  (5x5 zero-pad-2 conv, 64ch -> 64ch).
// grid: 512 blocks = b(2) | och_t(4b) | row_t(3b). Block: 4 och x 4 rows x 32 cols.
__global__ __launch_bounds__(256) void k_applyG(const float* __restrict__ vin,
                                                float* __restrict__ vout,
                                                const float* __restrict__ G) {
  __shared__ __align__(16) float sIn[2][8 * 40];
  int tid = threadIdx.x;
  int blk = blockIdx.x;
  int b = blk >> 7, och_t = (blk >> 3) & 15, row_t = blk & 7;
  int wv = __builtin_amdgcn_readfirstlane(tid >> 6);
  int och = och_t * 4 + wv;
  int row_l = (tid >> 4) & 3;
  int cg = tid & 15;
  for (int i = tid; i < 2 * 320; i += 256) ((float*)sIn)[i] = 0.f;
  bool stager = ((tid & 3) == 0);
  int task = tid >> 2;
  int srow = task >> 3, scg = task & 7;
  int gr = row_t * 4 - 2 + srow;
  bool srv = stager && gr >= 0 && gr < 32;
  const float* rbase = vin + ((long)(b * 64) * NPIX + (long)gr * 32 + scg * 4);
  float* sdst = &sIn[0][srow * 40 + 4 + scg * 4];
  const float* gb = G + (size_t)och * 64 * 32;
  float wA[28], wB[28];
  float acc0 = 0.f, acc1 = 0.f;
  float4 stg;
  if (srv) stg = *(const float4*)(rbase);
  wload(gb, 0, wA);
  __syncthreads();
  if (srv) *(float4*)(sdst) = stg;
  __syncthreads();
  for (int o = 0; o < 64; o += 2) {
    if (srv) stg = *(const float4*)(rbase + (size_t)(o + 1) * NPIX);
    wload(gb, o + 1, wB);
    conv5(sIn[0], row_l, cg, wA, acc0, acc1);
    if (srv) *(float4*)(sdst + 320) = stg;
    __syncthreads();
    bool more = (o + 2 < 64);
    if (more) {
      if (srv) stg = *(const float4*)(rbase + (size_t)(o + 2) * NPIX);
      wload(gb, o + 2, wA);
    }
    conv5(sIn[1], row_l, cg, wB, acc0, acc1);
    if (more && srv) *(float4*)(sdst) = stg;
    __syncthreads();
  }
  int gi = row_t * 4 + row_l;
  size_t own = ((size_t)(b * 64 + och) * 32 + gi) * 32 + cg * 2;
  float2 ov = {acc0, acc1};
  *(float2*)(vout + own) = ov;
}

// Gamma[i][j] = <v_i, v_j>. grid: 36 pairs x 8 slices = 288 blocks.
__global__ __launch_bounds__(256) void k_gamma(const float* __restrict__ V,
                                               float* __restrict__ Gam) {
  __shared__ float ws4[4];
  int tid = threadIdx.x;
  int p = blockIdx.x >> 3, slice = blockIdx.x & 7;
  int i = 0, rem = p;
  while (rem >= KRYLOV - i) { rem -= KRYLOV - i; ++i; }
  int j = i + rem;
  const float4* vi = (const float4*)(V + (size_t)i * VPLANE);
  const float4* vj = (const float4*)(V + (size_t)j * VPLANE);
  int base = slice * 8192;            // 65536 float4 total / 8 slices
  float acc = 0.f;
  for (int t = tid; t < 8192; t += 256) {
    float4 a = vi[base + t], c = vj[base + t];
    acc = fmaf(a.x, c.x, acc);
    acc = fmaf(a.y, c.y, acc);
    acc = fmaf(a.z, c.z, acc);
    acc = fmaf(a.w, c.w, acc);
  }
#pragma unroll
  for (int d = 32; d; d >>= 1) acc += __shfl_down(acc, d, 64);
  if ((tid & 63) == 0) ws4[tid >> 6] = acc;
  __syncthreads();
  if (tid == 0) {
    float tot = ws4[0] + ws4[1] + ws4[2] + ws4[3];
    atomicAdd(&Gam[i * KRYLOV + j], tot);
    if (i != j) atomicAdd(&Gam[j * KRYLOV + i], tot);
  }
}

// 500-step scalar recurrence in the Krylov basis. One wave.
//   c(0) = e_0;  e_t^2 = c^T Gam c;  alpha_t = LR/e_t;
//   d += alpha_t c;  c_j -= alpha_t c_{j-1}.
__global__ __launch_bounds__(64) void k_scalar(const float* __restrict__ Gam,
                                               float* __restrict__ dvec) {
  int lane = threadIdx.x;
  int j = lane & 7;
  float g[KRYLOV];
#pragma unroll
  for (int i = 0; i < KRYLOV; ++i) g[i] = Gam[i * KRYLOV + j];
  float c = (j == 0) ? 1.f : 0.f;
  float d = 0.f;
  for (int t = 0; t < NUM_ITERS; ++t) {
    float y = 0.f;
#pragma unroll
    for (int i = 0; i < KRYLOV; ++i) y = fmaf(g[i], __shfl(c, i, 64), y);
    float pr = c * y;
    pr += __shfl_xor(pr, 1, 64);
    pr += __shfl_xor(pr, 2, 64);
    pr += __shfl_xor(pr, 4, 64);      // e^2, uniform within each 8-lane group
    float alpha = LR_F / sqrtf(pr);
    d = fmaf(alpha, c, d);
    float cm1 = __shfl_up(c, 1, 64);
    c = (j == 0) ? c : fmaf(-alpha, cm1, c);
  }
  if (lane < KRYLOV) dvec[lane] = d;
}

// s = sum_j d_j v_j, written in place over v_0.
__global__ __launch_bounds__(256) void k_combine(float* __restrict__ V,
                                                 const float* __restrict__ dvec) {
  int idx = blockIdx.x * 256 + threadIdx.x;     // 65536 float4 elements
  float d[KRYLOV];
#pragma unroll
  for (int i = 0; i < KRYLOV; ++i) d[i] = dvec[i];
  float4 acc = {0.f, 0.f, 0.f, 0.f};
#pragma unroll
  for (int i = 0; i < KRYLOV; ++i) {
    float4 v = *(const float4*)(V + (size_t)i * VPLANE + (size_t)idx * 4);
    acc.x = fmaf(d[i], v.x, acc.x);
    acc.y = fmaf(d[i], v.y, acc.y);
    acc.z = fmaf(d[i], v.z, acc.z);
    acc.w = fmaf(d[i], v.w, acc.w);
  }
  *(float4*)(V + (size_t)idx * 4) = acc;
}

// out = yp0_interior + (A^T s)_interior + conv1x1(x, W_bypass). grid: 512 = (b<<7)|co
__global__ __launch_bounds__(256) void k_finalize(const float* __restrict__ x,
                                                  const float* __restrict__ Wfb,
                                                  const float* __restrict__ Wb,
                                                  const float* __restrict__ yp0,
                                                  const float* __restrict__ s,
                                                  float* __restrict__ out) {
  __shared__ __align__(16) float sA[34 * PITCH];
  __shared__ __align__(16) float sB[34 * PITCH];
  int tid = threadIdx.x;
  int b = blockIdx.x >> 7, co = blockIdx.x & 127;
  for (int i = tid; i < 34 * PITCH; i += 256) { sA[i] = 0.f; sB[i] = 0.f; }
  __syncthreads();
  int y = tid >> 3, x0 = (tid & 7) * 4;
  float acc[4] = {0.f, 0.f, 0.f, 0.f};
  const float* sb = s + (size_t)(b * 64) * NPIX;
  stage_x(sb, sA, tid);
  __syncthreads();
  for (int o = 0; o < 64; o += 2) {
    stage_x(sb + (size_t)(o + 1) * NPIX, sB, tid);
    {
      const float* wg = Wfb + (size_t)(co * 64 + o) * 9;
      float wf[9];
#pragma unroll
      for (int i = 0; i < 9; ++i) wf[i] = wg[8 - i];   // flipped 3x3
      conv_acc(sA, wf, y, x0, acc);
    }
    __syncthreads();
    if (o + 2 < 64) stage_x(sb + (size_t)(o + 2) * NPIX, sA, tid);
    {
      const float* wg = Wfb + (size_t)(co * 64 + o + 1) * 9;
      float wf[9];
#pragma unroll
      for (int i = 0; i < 9; ++i) wf[i] = wg[8 - i];
      conv_acc(sB, wf, y, x0, acc);
    }
    __syncthreads();
  }
  const float* xb = x + (size_t)(b * 64) * NPIX + y * 32 + x0;
  const float* wbp = Wb + co * 64;
  for (int ci = 0; ci < 64; ++ci) {
    float4 xv = *(const float4*)(xb + (size_t)ci * NPIX);
    float wvv = wbp[ci];
    acc[0] = fmaf(xv.x, wvv, acc[0]);
    acc[1] = fmaf(xv.y, wvv, acc[1]);
    acc[2] = fmaf(xv.z, wvv, acc[2]);
    acc[3] = fmaf(xv.w, wvv, acc[3]);
  }
  const float* ypp = yp0 + (size_t)(b * COUT + co) * YP_PLANE + (y + 1) * 34 + (x0 + 1);
  float4 ov = {acc[0] + ypp[0], acc[1] + ypp[1], acc[2] + ypp[2], acc[3] + ypp[3]};
  *(float4*)(out + (size_t)(b * COUT + co) * NPIX + y * 32 + x0) = ov;
}

// ---- launch -----------------------------------------------------------------

extern "C" void kernel_launch(void* const* d_in, const int* in_sizes, int n_in,
                              void* d_out, int out_size, void* d_ws, size_t ws_size,
                              hipStream_t stream) {
  const float* x   = (const float*)d_in[0];
  const float* Wff = (const float*)d_in[1];
  const float* Wfb = (const float*)d_in[2];
  const float* Wb  = (const float*)d_in[3];
  float* out = (float*)d_out;

  float* yp0  = (float*)d_ws;                      // 591872 floats
  float* V    = yp0 + (size_t)4 * COUT * YP_PLANE; // 8 * 262144 floats
  float* G5   = V + (size_t)KRYLOV * VPLANE;       // 131072 floats
  float* Gam  = G5 + (size_t)64 * 64 * 32;         // 64 floats
  float* dvec = Gam + 64;                          // 8 floats

  hipLaunchKernelGGL(k_init,    dim3(512), dim3(256), 0, stream, x, Wff, yp0, Gam);
  hipLaunchKernelGGL(k_gram,    dim3(64),  dim3(256), 0, stream, Wfb, G5);
  hipLaunchKernelGGL(k_forward, dim3(256), dim3(256), 0, stream, x, Wfb, yp0, V);
  for (int j = 0; j + 1 < KRYLOV; ++j) {
    hipLaunchKernelGGL(k_applyG, dim3(512), dim3(256), 0, stream,
                       V + (size_t)j * VPLANE, V + (size_t)(j + 1) * VPLANE, G5);
  }
  hipLaunchKernelGGL(k_gamma,   dim3(288), dim3(256), 0, stream, V, Gam);
  hipLaunchKernelGGL(k_scalar,  dim3(1),   dim3(64),  0, stream, Gam, dvec);
  hipLaunchKernelGGL(k_combine, dim3(256), dim3(256), 0, stream, V, dvec);
  hipLaunchKernelGGL(k_finalize, dim3(512), dim3(256), 0, stream, x, Wfb, Wb, yp0, V, out);
}

// Round 4
// 426.611 us; speedup vs baseline: 169.3502x; 1.6495x over previous
//
#include <hip/hip_runtime.h>

#define CIN 64
#define COUT 128
#define NPIX 1024        // 32*32
#define YP_PLANE 1156    // 34*34
#define PITCH 36         // LDS pitch for 34-wide planes
#define NUM_ITERS 500
#define LR_F 0.001f
#define KRYLOV 4
#define VPLANE 262144    // 4*64*1024 floats per Krylov vector

// ---- helpers ----------------------------------------------------------------

// Stage a 34x34 plane (contiguous 1156 floats, 16B-aligned) into pitch-36 LDS.
__device__ __forceinline__ void stage_plane34(const float* __restrict__ g, float* s, int tid) {
  for (int i4 = tid; i4 < 289; i4 += 256) {   // 289 float4 = 1156 floats
    float4 v = ((const float4*)g)[i4];
    int e = i4 * 4;
    int ry = e / 34, rx = e - ry * 34;
    float vv[4] = {v.x, v.y, v.z, v.w};
#pragma unroll
    for (int k = 0; k < 4; ++k) {
      s[ry * PITCH + rx] = vv[k];
      if (++rx == 34) { rx = 0; ++ry; }
    }
  }
}

// Stage a 32x32 plane into pitch-36 LDS at offset (+1,+1); border stays zero.
__device__ __forceinline__ void stage_x(const float* __restrict__ g, float* s, int tid) {
  int ry = tid >> 3, rx = (tid & 7) * 4;
  float4 v = *(const float4*)(g + ry * 32 + rx);
  float* d = s + (ry + 1) * PITCH + rx + 1;
  d[0] = v.x; d[1] = v.y; d[2] = v.z; d[3] = v.w;
}

// acc[k] += sum_{di,dj} s[(y+di)*PITCH + x0+k+dj] * w9[di*3+dj], k=0..3
__device__ __forceinline__ void conv_acc(const float* s, const float* __restrict__ w9,
                                         int y, int x0, float acc[4]) {
  float w[9];
#pragma unroll
  for (int i = 0; i < 9; ++i) w[i] = w9[i];
#pragma unroll
  for (int di = 0; di < 3; ++di) {
    const float* row = s + (y + di) * PITCH + x0;
    float4 v4 = *(const float4*)row;
    float2 v2 = *(const float2*)(row + 4);
    float v[6] = {v4.x, v4.y, v4.z, v4.w, v2.x, v2.y};
#pragma unroll
    for (int dj = 0; dj < 3; ++dj) {
      float wv = w[di * 3 + dj];
#pragma unroll
      for (int k = 0; k < 4; ++k) acc[k] = fmaf(v[k + dj], wv, acc[k]);
    }
  }
}

// load 25 (padded 28) weights for (och,o) from G row (stride 32, 16B aligned)
__device__ __forceinline__ void wload(const float* __restrict__ gb, int o, float w[28]) {
  const float4* g4 = (const float4*)(gb + o * 32);
#pragma unroll
  for (int i = 0; i < 7; ++i) {
    float4 v = g4[i];
    w[4 * i] = v.x; w[4 * i + 1] = v.y; w[4 * i + 2] = v.z; w[4 * i + 3] = v.w;
  }
}

// 5x5 conv tap loop: acc{0,1} for out cols cg*2 + {0,1}
__device__ __forceinline__ void conv5(const float* sbuf, int row_l, int cg, const float w[28],
                                      float& acc0, float& acc1) {
#pragma unroll
  for (int wr = 0; wr < 5; ++wr) {
    const float* rp = sbuf + (row_l + wr) * 40 + cg * 2 + 2;
    float2 p0 = *(const float2*)rp;
    float2 p1 = *(const float2*)(rp + 2);
    float2 p2 = *(const float2*)(rp + 4);
    float v[6] = {p0.x, p0.y, p1.x, p1.y, p2.x, p2.y};
#pragma unroll
    for (int vc = 0; vc < 5; ++vc) {
      acc0 = fmaf(w[wr * 5 + vc], v[vc], acc0);
      acc1 = fmaf(w[wr * 5 + vc], v[vc + 1], acc1);
    }
  }
}

// ---- kernels ----------------------------------------------------------------

// Init: yp0 = pad(relu(conv3x3(x, W_ff, pad1))); block 0 zeroes Gamma[64].
__global__ __launch_bounds__(256) void k_init(const float* __restrict__ x,
                                              const float* __restrict__ Wff,
                                              float* __restrict__ yp,
                                              float* __restrict__ Gam) {
  __shared__ __align__(16) float sA[34 * PITCH];
  __shared__ __align__(16) float sB[34 * PITCH];
  int tid = threadIdx.x;
  int b = blockIdx.x >> 7, c = blockIdx.x & 127;
  if (blockIdx.x == 0 && tid < 64) Gam[tid] = 0.f;
  for (int i = tid; i < 34 * PITCH; i += 256) { sA[i] = 0.f; sB[i] = 0.f; }
  __syncthreads();
  int y = tid >> 3, x0 = (tid & 7) * 4;
  float acc[4] = {0.f, 0.f, 0.f, 0.f};
  const float* xb = x + (size_t)(b * CIN) * NPIX;
  stage_x(xb, sA, tid);
  __syncthreads();
  for (int ci = 0; ci < CIN; ci += 2) {
    stage_x(xb + (size_t)(ci + 1) * NPIX, sB, tid);
    conv_acc(sA, Wff + (size_t)(c * CIN + ci) * 9, y, x0, acc);
    __syncthreads();
    if (ci + 2 < CIN) stage_x(xb + (size_t)(ci + 2) * NPIX, sA, tid);
    conv_acc(sB, Wff + (size_t)(c * CIN + ci + 1) * 9, y, x0, acc);
    __syncthreads();
  }
  float* ypp = yp + (size_t)(b * COUT + c) * YP_PLANE;
  for (int i = tid; i < YP_PLANE; i += 256) {
    int p = i / 34, q = i - p * 34;
    if (p == 0 || p == 33 || q == 0 || q == 33) ypp[i] = 0.f;
  }
#pragma unroll
  for (int k = 0; k < 4; ++k) {
    float v = acc[k] > 0.f ? acc[k] : 0.f;
    ypp[(y + 1) * 34 + (x0 + 1 + k)] = v;
  }
}

// Gram conv kernel: G[o'*64+o][tap] (tap=(u+2)*5+(v+2), row stride 32)
//   = sum_c sum_{ei,ej} Wfb[c,o',ei,ej] * Wfb[c,o,ei-u,ej-v]
__global__ __launch_bounds__(256) void k_gram(const float* __restrict__ Wfb,
                                              float* __restrict__ G) {
  __shared__ float wA[128 * 9];
  __shared__ float gred[256][25];
  int tid = threadIdx.x;
  int op = blockIdx.x;  // o' in [0,64)
  for (int i = tid; i < 1152; i += 256) {
    int c = i / 9, k = i - c * 9;
    wA[i] = Wfb[(size_t)(c * 64 + op) * 9 + k];
  }
  __syncthreads();
  int o = tid & 63, part = tid >> 6;
  float g[25];
#pragma unroll
  for (int i = 0; i < 25; ++i) g[i] = 0.f;
  for (int c = part * 32; c < part * 32 + 32; ++c) {
    float b9[9];
#pragma unroll
    for (int k = 0; k < 9; ++k) b9[k] = Wfb[(size_t)(c * 64 + o) * 9 + k];
    const float* a9 = &wA[c * 9];
#pragma unroll
    for (int ei = 0; ei < 3; ++ei)
#pragma unroll
      for (int ej = 0; ej < 3; ++ej) {
        float av = a9[ei * 3 + ej];
#pragma unroll
        for (int di = 0; di < 3; ++di)
#pragma unroll
          for (int dj = 0; dj < 3; ++dj)
            g[(ei - di + 2) * 5 + (ej - dj + 2)] = fmaf(av, b9[di * 3 + dj],
                                                        g[(ei - di + 2) * 5 + (ej - dj + 2)]);
      }
  }
#pragma unroll
  for (int i = 0; i < 25; ++i) gred[tid][i] = g[i];
  __syncthreads();
  if (part == 0) {
    float* dst = G + ((size_t)op * 64 + o) * 32;
#pragma unroll
    for (int i = 0; i < 25; ++i)
      dst[i] = gred[tid][i] + gred[tid + 64][i] + gred[tid + 128][i] + gred[tid + 192][i];
  }
}

// v0 = r0 = x - conv_valid(yp0, Wfb[c][o]). grid: 256 blocks = (b<<6)|o
__global__ __launch_bounds__(256) void k_forward(const float* __restrict__ x,
                                                 const float* __restrict__ Wfb,
                                                 const float* __restrict__ yp,
                                                 float* __restrict__ v0) {
  __shared__ __align__(16) float sA[34 * PITCH];
  __shared__ __align__(16) float sB[34 * PITCH];
  int tid = threadIdx.x;
  int b = blockIdx.x >> 6, o = blockIdx.x & 63;
  int y = tid >> 3, x0 = (tid & 7) * 4;
  float acc[4] = {0.f, 0.f, 0.f, 0.f};
  const float* ypb = yp + (size_t)(b * COUT) * YP_PLANE;
  stage_plane34(ypb, sA, tid);
  __syncthreads();
  for (int c = 0; c < COUT; c += 2) {
    stage_plane34(ypb + (size_t)(c + 1) * YP_PLANE, sB, tid);
    conv_acc(sA, Wfb + (size_t)(c * CIN + o) * 9, y, x0, acc);
    __syncthreads();
    if (c + 2 < COUT) stage_plane34(ypb + (size_t)(c + 2) * YP_PLANE, sA, tid);
    conv_acc(sB, Wfb + (size_t)((c + 1) * CIN + o) * 9, y, x0, acc);
    __syncthreads();
  }
  size_t off = (size_t)(b * CIN + o) * NPIX + y * 32 + x0;
  float4 xv = *(const float4*)(x + off);
  float4 rv = {xv.x - acc[0], xv.y - acc[1], xv.z - acc[2], xv.w - acc[3]};
  *(float4*)(v0 + off) = rv;
}

// v_{j+1} = G (*) v_j  (5x5 zero-pad-2 conv, 64ch -> 64ch).
// grid: 512 blocks = b(2) | och_t(4b) | row_t(3b). Block: 4 och x 4 rows x 32 cols.
__global__ __launch_bounds__(256) void k_applyG(const float* __restrict__ vin,
                                                float* __restrict__ vout,
                                                const float* __restrict__ G) {
  __shared__ __align__(16) float sIn[2][8 * 40];
  int tid = threadIdx.x;
  int blk = blockIdx.x;
  int b = blk >> 7, och_t = (blk >> 3) & 15, row_t = blk & 7;
  int wv = __builtin_amdgcn_readfirstlane(tid >> 6);
  int och = och_t * 4 + wv;
  int row_l = (tid >> 4) & 3;
  int cg = tid & 15;
  for (int i = tid; i < 2 * 320; i += 256) ((float*)sIn)[i] = 0.f;
  bool stager = ((tid & 3) == 0);
  int task = tid >> 2;
  int srow = task >> 3, scg = task & 7;
  int gr = row_t * 4 - 2 + srow;
  bool srv = stager && gr >= 0 && gr < 32;
  const float* rbase = vin + ((long)(b * 64) * NPIX + (long)gr * 32 + scg * 4);
  float* sdst = &sIn[0][srow * 40 + 4 + scg * 4];
  const float* gb = G + (size_t)och * 64 * 32;
  float wA[28], wB[28];
  float acc0 = 0.f, acc1 = 0.f;
  float4 stg;
  if (srv) stg = *(const float4*)(rbase);
  wload(gb, 0, wA);
  __syncthreads();
  if (srv) *(float4*)(sdst) = stg;
  __syncthreads();
  for (int o = 0; o < 64; o += 2) {
    if (srv) stg = *(const float4*)(rbase + (size_t)(o + 1) * NPIX);
    wload(gb, o + 1, wB);
    conv5(sIn[0], row_l, cg, wA, acc0, acc1);
    if (srv) *(float4*)(sdst + 320) = stg;
    __syncthreads();
    bool more = (o + 2 < 64);
    if (more) {
      if (srv) stg = *(const float4*)(rbase + (size_t)(o + 2) * NPIX);
      wload(gb, o + 2, wA);
    }
    conv5(sIn[1], row_l, cg, wB, acc0, acc1);
    if (more && srv) *(float4*)(sdst) = stg;
    __syncthreads();
  }
  int gi = row_t * 4 + row_l;
  size_t own = ((size_t)(b * 64 + och) * 32 + gi) * 32 + cg * 2;
  float2 ov = {acc0, acc1};
  *(float2*)(vout + own) = ov;
}

// Gamma[i][j] = <v_i, v_j>. grid: 10 pairs x 8 slices = 80 blocks.
__global__ __launch_bounds__(256) void k_gamma(const float* __restrict__ V,
                                               float* __restrict__ Gam) {
  __shared__ float ws4[4];
  int tid = threadIdx.x;
  int p = blockIdx.x >> 3, slice = blockIdx.x & 7;
  int i = 0, rem = p;
  while (rem >= KRYLOV - i) { rem -= KRYLOV - i; ++i; }
  int j = i + rem;
  const float4* vi = (const float4*)(V + (size_t)i * VPLANE);
  const float4* vj = (const float4*)(V + (size_t)j * VPLANE);
  int base = slice * 8192;            // 65536 float4 total / 8 slices
  float acc = 0.f;
  for (int t = tid; t < 8192; t += 256) {
    float4 a = vi[base + t], c = vj[base + t];
    acc = fmaf(a.x, c.x, acc);
    acc = fmaf(a.y, c.y, acc);
    acc = fmaf(a.z, c.z, acc);
    acc = fmaf(a.w, c.w, acc);
  }
#pragma unroll
  for (int d = 32; d; d >>= 1) acc += __shfl_down(acc, d, 64);
  if ((tid & 63) == 0) ws4[tid >> 6] = acc;
  __syncthreads();
  if (tid == 0) {
    float tot = ws4[0] + ws4[1] + ws4[2] + ws4[3];
    atomicAdd(&Gam[i * KRYLOV + j], tot);
    if (i != j) atomicAdd(&Gam[j * KRYLOV + i], tot);
  }
}

// 500-step scalar recurrence in the 4-dim Krylov basis, fully replicated
// per-lane (no cross-lane ops, no LDS): 18 state floats in registers.
//   c(0) = [1,0,0,0];  e_t^2 = c^T Gam c;  alpha_t = LR * rsq(e^2);
//   d += alpha_t c;  c_j -= alpha_t c_{j-1}.
__global__ __launch_bounds__(64) void k_scalar(const float* __restrict__ Gam,
                                               float* __restrict__ dvec) {
  float g00 = Gam[0],  g01 = Gam[1],  g02 = Gam[2],  g03 = Gam[3];
  float g11 = Gam[5],  g12 = Gam[6],  g13 = Gam[7];
  float g22 = Gam[10], g23 = Gam[11], g33 = Gam[15];
  float c0 = 1.f, c1 = 0.f, c2 = 0.f, c3 = 0.f;
  float d0 = 0.f, d1 = 0.f, d2 = 0.f, d3 = 0.f;
  for (int t = 0; t < NUM_ITERS; ++t) {
    float y0 = fmaf(g00, c0, fmaf(g01, c1, fmaf(g02, c2, g03 * c3)));
    float y1 = fmaf(g01, c0, fmaf(g11, c1, fmaf(g12, c2, g13 * c3)));
    float y2 = fmaf(g02, c0, fmaf(g12, c1, fmaf(g22, c2, g23 * c3)));
    float y3 = fmaf(g03, c0, fmaf(g13, c1, fmaf(g23, c2, g33 * c3)));
    float pr = fmaf(c0, y0, fmaf(c1, y1, fmaf(c2, y2, c3 * y3)));
    float alpha = LR_F * __builtin_amdgcn_rsqf(pr);
    d0 = fmaf(alpha, c0, d0);
    d1 = fmaf(alpha, c1, d1);
    d2 = fmaf(alpha, c2, d2);
    d3 = fmaf(alpha, c3, d3);
    c3 = fmaf(-alpha, c2, c3);
    c2 = fmaf(-alpha, c1, c2);
    c1 = fmaf(-alpha, c0, c1);
  }
  if (threadIdx.x == 0) {
    dvec[0] = d0; dvec[1] = d1; dvec[2] = d2; dvec[3] = d3;
  }
}

// s = sum_j d_j v_j, written in place over v_0.
__global__ __launch_bounds__(256) void k_combine(float* __restrict__ V,
                                                 const float* __restrict__ dvec) {
  int idx = blockIdx.x * 256 + threadIdx.x;     // 65536 float4 elements
  float d[KRYLOV];
#pragma unroll
  for (int i = 0; i < KRYLOV; ++i) d[i] = dvec[i];
  float4 acc = {0.f, 0.f, 0.f, 0.f};
#pragma unroll
  for (int i = 0; i < KRYLOV; ++i) {
    float4 v = *(const float4*)(V + (size_t)i * VPLANE + (size_t)idx * 4);
    acc.x = fmaf(d[i], v.x, acc.x);
    acc.y = fmaf(d[i], v.y, acc.y);
    acc.z = fmaf(d[i], v.z, acc.z);
    acc.w = fmaf(d[i], v.w, acc.w);
  }
  *(float4*)(V + (size_t)idx * 4) = acc;
}

// out = yp0_interior + (A^T s)_interior + conv1x1(x, W_bypass). grid: 512 = (b<<7)|co
__global__ __launch_bounds__(256) void k_finalize(const float* __restrict__ x,
                                                  const float* __restrict__ Wfb,
                                                  const float* __restrict__ Wb,
                                                  const float* __restrict__ yp0,
                                                  const float* __restrict__ s,
                                                  float* __restrict__ out) {
  __shared__ __align__(16) float sA[34 * PITCH];
  __shared__ __align__(16) float sB[34 * PITCH];
  int tid = threadIdx.x;
  int b = blockIdx.x >> 7, co = blockIdx.x & 127;
  for (int i = tid; i < 34 * PITCH; i += 256) { sA[i] = 0.f; sB[i] = 0.f; }
  __syncthreads();
  int y = tid >> 3, x0 = (tid & 7) * 4;
  float acc[4] = {0.f, 0.f, 0.f, 0.f};
  const float* sb = s + (size_t)(b * 64) * NPIX;
  stage_x(sb, sA, tid);
  __syncthreads();
  for (int o = 0; o < 64; o += 2) {
    stage_x(sb + (size_t)(o + 1) * NPIX, sB, tid);
    {
      const float* wg = Wfb + (size_t)(co * 64 + o) * 9;
      float wf[9];
#pragma unroll
      for (int i = 0; i < 9; ++i) wf[i] = wg[8 - i];   // flipped 3x3
      conv_acc(sA, wf, y, x0, acc);
    }
    __syncthreads();
    if (o + 2 < 64) stage_x(sb + (size_t)(o + 2) * NPIX, sA, tid);
    {
      const float* wg = Wfb + (size_t)(co * 64 + o + 1) * 9;
      float wf[9];
#pragma unroll
      for (int i = 0; i < 9; ++i) wf[i] = wg[8 - i];
      conv_acc(sB, wf, y, x0, acc);
    }
    __syncthreads();
  }
  const float* xb = x + (size_t)(b * 64) * NPIX + y * 32 + x0;
  const float* wbp = Wb + co * 64;
  for (int ci = 0; ci < 64; ++ci) {
    float4 xv = *(const float4*)(xb + (size_t)ci * NPIX);
    float wvv = wbp[ci];
    acc[0] = fmaf(xv.x, wvv, acc[0]);
    acc[1] = fmaf(xv.y, wvv, acc[1]);
    acc[2] = fmaf(xv.z, wvv, acc[2]);
    acc[3] = fmaf(xv.w, wvv, acc[3]);
  }
  const float* ypp = yp0 + (size_t)(b * COUT + co) * YP_PLANE + (y + 1) * 34 + (x0 + 1);
  float4 ov = {acc[0] + ypp[0], acc[1] + ypp[1], acc[2] + ypp[2], acc[3] + ypp[3]};
  *(float4*)(out + (size_t)(b * COUT + co) * NPIX + y * 32 + x0) = ov;
}

// ---- launch -----------------------------------------------------------------

extern "C" void kernel_launch(void* const* d_in, const int* in_sizes, int n_in,
                              void* d_out, int out_size, void* d_ws, size_t ws_size,
                              hipStream_t stream) {
  const float* x   = (const float*)d_in[0];
  const float* Wff = (const float*)d_in[1];
  const float* Wfb = (const float*)d_in[2];
  const float* Wb  = (const float*)d_in[3];
  float* out = (float*)d_out;

  float* yp0  = (float*)d_ws;                      // 591872 floats
  float* V    = yp0 + (size_t)4 * COUT * YP_PLANE; // KRYLOV * 262144 floats
  float* G5   = V + (size_t)KRYLOV * VPLANE;       // 131072 floats
  float* Gam  = G5 + (size_t)64 * 64 * 32;         // 64 floats
  float* dvec = Gam + 64;                          // KRYLOV floats

  hipLaunchKernelGGL(k_init,    dim3(512), dim3(256), 0, stream, x, Wff, yp0, Gam);
  hipLaunchKernelGGL(k_gram,    dim3(64),  dim3(256), 0, stream, Wfb, G5);
  hipLaunchKernelGGL(k_forward, dim3(256), dim3(256), 0, stream, x, Wfb, yp0, V);
  for (int j = 0; j + 1 < KRYLOV; ++j) {
    hipLaunchKernelGGL(k_applyG, dim3(512), dim3(256), 0, stream,
                       V + (size_t)j * VPLANE, V + (size_t)(j + 1) * VPLANE, G5);
  }
  hipLaunchKernelGGL(k_gamma,   dim3(80),  dim3(256), 0, stream, V, Gam);
  hipLaunchKernelGGL(k_scalar,  dim3(1),   dim3(64),  0, stream, Gam, dvec);
  hipLaunchKernelGGL(k_combine, dim3(256), dim3(256), 0, stream, V, dvec);
  hipLaunchKernelGGL(k_finalize, dim3(512), dim3(256), 0, stream, x, Wfb, Wb, yp0, V, out);
}